// Round 10
// baseline (111.290 us; speedup 1.0000x reference)
//
#include <hip/hip_runtime.h>
#include <hip/hip_bf16.h>
#include <math.h>

#define BB 8
#define SS 160
#define HH 768
#define DEPTH 64
#define NHEAD 12
#define DHEAD 64
#define BS (BB*SS)

constexpr float EPS_C = 1e-5f;

typedef __attribute__((ext_vector_type(8))) short bf16x8;
typedef __attribute__((ext_vector_type(4))) float f32x4;

__device__ inline short f2bs(float x) {
    union { __hip_bfloat16 b; short s; } u;
    u.b = __float2bfloat16(x);
    return u.s;
}
__device__ inline float bs2f(short s) {
    union { short s; __hip_bfloat16 b; } u;
    u.s = s;
    return __bfloat162float(u.b);
}

// ---------------- cast X (f32 -> bf16, row-major) ----------------
__global__ __launch_bounds__(256) void cast_x(
    const float* __restrict__ X, __hip_bfloat16* __restrict__ Xb)
{
    int idx = blockIdx.x * 256 + threadIdx.x;      // 245760 float4 items
    float4 xin = ((const float4*)X)[idx];
    __hip_bfloat16* o = Xb + (size_t)idx * 4;
    o[0] = __float2bfloat16(xin.x); o[1] = __float2bfloat16(xin.y);
    o[2] = __float2bfloat16(xin.z); o[3] = __float2bfloat16(xin.w);
}

// ---------------- transpose+cast W[k][n] f32 -> WT[n][k] bf16 ----------------
__global__ __launch_bounds__(256) void transpose_cast_w(
    const float* __restrict__ Wq, const float* __restrict__ Wk,
    const float* __restrict__ Wv, __hip_bfloat16* __restrict__ WT)
{
    __shared__ float t[32][33];
    const float* W = (blockIdx.z == 0) ? Wq : (blockIdx.z == 1) ? Wk : Wv;
    __hip_bfloat16* o = WT + (size_t)blockIdx.z * HH * HH;
    int kt = blockIdx.x * 32, nt = blockIdx.y * 32;
    int tx = threadIdx.x & 31, ty = threadIdx.x >> 5;   // ty 0..7
#pragma unroll
    for (int r = 0; r < 32; r += 8)
        t[ty + r][tx] = W[(size_t)(kt + ty + r) * HH + nt + tx];
    __syncthreads();
#pragma unroll
    for (int r = 0; r < 32; r += 8)
        o[(size_t)(nt + ty + r) * HH + kt + tx] = __float2bfloat16(t[tx][ty + r]);
}

// ---------------- MFMA GEMM: {q,k,v} = X @ W + b (bf16 in, f32 acc) ----------
__global__ __launch_bounds__(256) void gemm_qkv(
    const __hip_bfloat16* __restrict__ Xb, const __hip_bfloat16* __restrict__ WT,
    const float* __restrict__ bq, const float* __restrict__ bk,
    const float* __restrict__ bv,
    __hip_bfloat16* __restrict__ qb, __hip_bfloat16* __restrict__ kb,
    __hip_bfloat16* __restrict__ vb)
{
    __shared__ int4 sA[4][128];   // 8 KB
    __shared__ int4 sB[4][64];    // 4 KB
    int m0 = blockIdx.x * 128, n0 = blockIdx.y * 64, mat = blockIdx.z;
    const short* X = (const short*)Xb;
    const short* W = (const short*)WT + (size_t)mat * HH * HH;
    const float* bias = (mat == 0) ? bq : (mat == 1) ? bk : bv;
    int tid = threadIdx.x, w = tid >> 6, l = tid & 63;
    int wm = (w >> 1) * 64, wn = (w & 1) * 32;
    int khalf = l >> 4, lc = l & 15;

    f32x4 acc[4][2];
#pragma unroll
    for (int i = 0; i < 4; i++)
#pragma unroll
        for (int j = 0; j < 2; j++) acc[i][j] = (f32x4){0.f, 0.f, 0.f, 0.f};

    for (int k0 = 0; k0 < HH; k0 += 32) {
        __syncthreads();
        sA[w][l]      = *(const int4*)(X + (size_t)(m0 + l) * HH + k0 + w * 8);
        sA[w][l + 64] = *(const int4*)(X + (size_t)(m0 + l + 64) * HH + k0 + w * 8);
        sB[w][l]      = *(const int4*)(W + (size_t)(n0 + l) * HH + k0 + w * 8);
        __syncthreads();
        bf16x8 b0 = *(const bf16x8*)&sB[khalf][wn + lc];
        bf16x8 b1 = *(const bf16x8*)&sB[khalf][wn + 16 + lc];
#pragma unroll
        for (int mi = 0; mi < 4; mi++) {
            bf16x8 a = *(const bf16x8*)&sA[khalf][wm + mi * 16 + lc];
            acc[mi][0] = __builtin_amdgcn_mfma_f32_16x16x32_bf16(a, b0, acc[mi][0], 0, 0, 0);
            acc[mi][1] = __builtin_amdgcn_mfma_f32_16x16x32_bf16(a, b1, acc[mi][1], 0, 0, 0);
        }
    }

    int rg = (l >> 4) * 4;
    __hip_bfloat16* outm = (mat == 0) ? qb : (mat == 1) ? kb : vb;
#pragma unroll
    for (int ni = 0; ni < 2; ni++) {
        int gcol = n0 + wn + ni * 16 + lc;
        float bv_ = bias[gcol];
#pragma unroll
        for (int mi = 0; mi < 4; mi++) {
            int grow = m0 + wm + mi * 16 + rg;
            f32x4 a = acc[mi][ni];
            __hip_bfloat16* o = outm + (size_t)grow * HH + gcol;
            o[0]      = __float2bfloat16(a.x + bv_);
            o[HH]     = __float2bfloat16(a.y + bv_);
            o[2 * HH] = __float2bfloat16(a.z + bv_);
            o[3 * HH] = __float2bfloat16(a.w + bv_);
        }
    }
}

// ---------------- MFMA scores: S[b][h] = (Q_h K_h^T) * 0.125, f16 out -------
__global__ __launch_bounds__(256) void scores_gemm(
    const __hip_bfloat16* __restrict__ qb, const __hip_bfloat16* __restrict__ kb,
    _Float16* __restrict__ sc)
{
    __shared__ int4 sQ[8][160];   // 20.5 KB
    __shared__ int4 sK[8][160];
    int h = blockIdx.x, b = blockIdx.y;
    const short* Q = (const short*)qb + (size_t)b * SS * HH + h * DHEAD;
    const short* K = (const short*)kb + (size_t)b * SS * HH + h * DHEAD;
    int tid = threadIdx.x, w = tid >> 6, l = tid & 63;

    for (int idx = tid; idx < SS * 8; idx += 256) {
        int row = idx >> 3, ch = idx & 7;
        sQ[ch][row] = *(const int4*)(Q + (size_t)row * HH + ch * 8);
        sK[ch][row] = *(const int4*)(K + (size_t)row * HH + ch * 8);
    }
    __syncthreads();

    int wm = (w >> 1) * 80, wn = (w & 1) * 80;
    int khalf = l >> 4, lc = l & 15;
    f32x4 acc[5][5];
#pragma unroll
    for (int i = 0; i < 5; i++)
#pragma unroll
        for (int j = 0; j < 5; j++) acc[i][j] = (f32x4){0.f, 0.f, 0.f, 0.f};

#pragma unroll
    for (int s = 0; s < 2; s++) {
        int c = s * 4 + khalf;
        bf16x8 bf[5];
#pragma unroll
        for (int ni = 0; ni < 5; ni++)
            bf[ni] = *(const bf16x8*)&sK[c][wn + ni * 16 + lc];
#pragma unroll
        for (int mi = 0; mi < 5; mi++) {
            bf16x8 a = *(const bf16x8*)&sQ[c][wm + mi * 16 + lc];
#pragma unroll
            for (int ni = 0; ni < 5; ni++)
                acc[mi][ni] = __builtin_amdgcn_mfma_f32_16x16x32_bf16(a, bf[ni], acc[mi][ni], 0, 0, 0);
        }
    }

    int rg = (l >> 4) * 4;
    _Float16* base = sc + (size_t)(b * NHEAD + h) * SS * SS;
#pragma unroll
    for (int mi = 0; mi < 5; mi++) {
        int i0 = wm + mi * 16 + rg;
#pragma unroll
        for (int ni = 0; ni < 5; ni++) {
            int j = wn + ni * 16 + lc;
            f32x4 a = acc[mi][ni];
            base[(size_t)(i0 + 0) * SS + j] = (_Float16)(a.x * 0.125f);
            base[(size_t)(i0 + 1) * SS + j] = (_Float16)(a.y * 0.125f);
            base[(size_t)(i0 + 2) * SS + j] = (_Float16)(a.z * 0.125f);
            base[(size_t)(i0 + 3) * SS + j] = (_Float16)(a.w * 0.125f);
        }
    }
}

// ---------------- qek_slim: qek[bi][h][d] = Wek_h^T q_h (bf16 out) ----------
// Block per (h, 8-m-tile group): Wek_h staged ONCE into LDS as packed bf16
// B-fragments (65-padded -> 2-way-free reads). 16 MFMA per wave.
__global__ __launch_bounds__(256) void qek_slim(
    const __hip_bfloat16* __restrict__ qb, const float* __restrict__ Wek,
    __hip_bfloat16* __restrict__ qek)
{
    __shared__ short sW[8 * 65 * 8];   // [chunk][dpad 65][8k] = 8.1 KB
    int h = blockIdx.x, mg = blockIdx.y;
    int tid = threadIdx.x, w = tid >> 6, l = tid & 63;
    int lr = l & 15, kg = l >> 4;

    // stage Wek_h (64d x 64c f32, coalesced) -> bf16 frag layout
    {
        int d = tid >> 2, q4 = tid & 3;
        const float* wp = Wek + (size_t)d * HH + h * DHEAD + q4 * 16;
        float4 w0 = *(const float4*)(wp);
        float4 w1 = *(const float4*)(wp + 4);
        float4 w2 = *(const float4*)(wp + 8);
        float4 w3 = *(const float4*)(wp + 12);
        bf16x8 p0, p1;
        p0[0]=f2bs(w0.x); p0[1]=f2bs(w0.y); p0[2]=f2bs(w0.z); p0[3]=f2bs(w0.w);
        p0[4]=f2bs(w1.x); p0[5]=f2bs(w1.y); p0[6]=f2bs(w1.z); p0[7]=f2bs(w1.w);
        p1[0]=f2bs(w2.x); p1[1]=f2bs(w2.y); p1[2]=f2bs(w2.z); p1[3]=f2bs(w2.w);
        p1[4]=f2bs(w3.x); p1[5]=f2bs(w3.y); p1[6]=f2bs(w3.z); p1[7]=f2bs(w3.w);
        *(bf16x8*)&sW[((q4 * 2) * 65 + d) * 8]     = p0;
        *(bf16x8*)&sW[((q4 * 2 + 1) * 65 + d) * 8] = p1;
    }
    __syncthreads();

    bf16x8 bfrag[2][4];
#pragma unroll
    for (int s = 0; s < 2; s++)
#pragma unroll
        for (int nt = 0; nt < 4; nt++)
            bfrag[s][nt] = *(const bf16x8*)&sW[((s * 4 + kg) * 65 + nt * 16 + lr) * 8];

    const short* Q = (const short*)qb;
    short* O = (short*)qek;
#pragma unroll
    for (int mi = 0; mi < 2; mi++) {
        int m0 = (mg * 8 + w * 2 + mi) * 16;
        bf16x8 a0 = *(const bf16x8*)(Q + (size_t)(m0 + lr) * HH + h * DHEAD + kg * 8);
        bf16x8 a1 = *(const bf16x8*)(Q + (size_t)(m0 + lr) * HH + h * DHEAD + 32 + kg * 8);
#pragma unroll
        for (int nt = 0; nt < 4; nt++) {
            f32x4 acc = (f32x4){0.f, 0.f, 0.f, 0.f};
            acc = __builtin_amdgcn_mfma_f32_16x16x32_bf16(a0, bfrag[0][nt], acc, 0, 0, 0);
            acc = __builtin_amdgcn_mfma_f32_16x16x32_bf16(a1, bfrag[1][nt], acc, 0, 0, 0);
            int row0 = m0 + kg * 4;
#pragma unroll
            for (int r = 0; r < 4; r++)
                O[(size_t)(row0 + r) * HH + h * DHEAD + nt * 16 + lr] = f2bs(acc[r]);
        }
    }
}

// ---------------- Fused attention + in-block escore + LayerNorm ----------------
// One block per (b,i). Scores = sc(qk) + qbek + MFMA e.qek (accumulated in LDS).
__global__ __launch_bounds__(256) void attn_kernel(
    const float* __restrict__ token, const float* __restrict__ edge,
    const int* __restrict__ mask,
    const __hip_bfloat16* __restrict__ q_ws, const _Float16* __restrict__ sc,
    const __hip_bfloat16* __restrict__ v_ws, const __hip_bfloat16* __restrict__ qek,
    const float* __restrict__ bek,
    const float* __restrict__ Wev, const float* __restrict__ bev,
    const float* __restrict__ ln_g, const float* __restrict__ ln_b,
    float* __restrict__ out)
{
    __shared__ float  s_ctx[HH];             // ctx_v
    __shared__ float  s_scores[NHEAD][SS];   // scores -> probs
    __shared__ float  s_pe[NHEAD][DEPTH];    // p . e
    __shared__ float  s_x[HH];               // pre-LN row
    __shared__ float  s_qbek[NHEAD];
    __shared__ int    s_mask[SS];
    __shared__ float  s_red[8];

    int bi = blockIdx.x;                     // b*S + i
    int b  = bi / SS;
    int i  = bi - b * SS;
    int tid = threadIdx.x;
    int w = tid >> 6, l = tid & 63;
    int lr = l & 15, kg = l >> 4;

    if (tid < SS) s_mask[tid] = mask[(size_t)bi * SS + tid];

    // ---- qbek[h] = q_h . bek_h : 16-lane cooperative dot ----
    {
        int hs = w * 3 + kg;                 // 0..14; valid < 12
        float part = 0.f;
        if (hs < NHEAD) {
            const __hip_bfloat16* qp = q_ws + (size_t)bi * HH + hs * DHEAD + lr * 4;
            float4 bv4 = *(const float4*)(bek + hs * DHEAD + lr * 4);
            part = __bfloat162float(qp[0]) * bv4.x + __bfloat162float(qp[1]) * bv4.y
                 + __bfloat162float(qp[2]) * bv4.z + __bfloat162float(qp[3]) * bv4.w;
        }
        part += __shfl_xor(part, 1, 64);
        part += __shfl_xor(part, 2, 64);
        part += __shfl_xor(part, 4, 64);
        part += __shfl_xor(part, 8, 64);
        if (lr == 0 && hs < NHEAD) s_qbek[hs] = part;
    }
    __syncthreads();

    // ---- assemble scores: qk(ws) + qbek, masked ----
    const _Float16* scp = sc + (size_t)(b * NHEAD) * (SS * SS) + (size_t)i * SS;
    for (int idx = tid; idx < NHEAD * SS; idx += 256) {
        int h = idx / SS, j = idx - h * SS;
        float qk = (float)scp[(size_t)h * (SS * SS) + j];
        s_scores[h][j] = s_mask[j] ? (qk + 0.125f * s_qbek[h]) : -10000.0f;
    }
    __syncthreads();

    // ---- escore MFMA: s_scores[h][j] += 0.125 * e[j,:].qek[h,:] ----
    const float* e_row = edge + (size_t)bi * SS * DEPTH;
    {
        const short* QE = (const short*)qek + (size_t)bi * HH;
        bf16x8 qe0 = *(const bf16x8*)(QE + lr * DHEAD + kg * 8);
        bf16x8 qe1 = *(const bf16x8*)(QE + lr * DHEAD + 32 + kg * 8);
        for (int jt = w; jt < 10; jt += 4) {
            const float* ep = e_row + (size_t)(jt * 16 + lr) * DEPTH + kg * 8;
            float4 e0 = *(const float4*)(ep);
            float4 e1 = *(const float4*)(ep + 4);
            float4 e2 = *(const float4*)(ep + 32);
            float4 e3 = *(const float4*)(ep + 36);
            bf16x8 a0, a1;
            a0[0]=f2bs(e0.x); a0[1]=f2bs(e0.y); a0[2]=f2bs(e0.z); a0[3]=f2bs(e0.w);
            a0[4]=f2bs(e1.x); a0[5]=f2bs(e1.y); a0[6]=f2bs(e1.z); a0[7]=f2bs(e1.w);
            a1[0]=f2bs(e2.x); a1[1]=f2bs(e2.y); a1[2]=f2bs(e2.z); a1[3]=f2bs(e2.w);
            a1[4]=f2bs(e3.x); a1[5]=f2bs(e3.y); a1[6]=f2bs(e3.z); a1[7]=f2bs(e3.w);
            f32x4 acc = (f32x4){0.f, 0.f, 0.f, 0.f};
            acc = __builtin_amdgcn_mfma_f32_16x16x32_bf16(a0, qe0, acc, 0, 0, 0);
            acc = __builtin_amdgcn_mfma_f32_16x16x32_bf16(a1, qe1, acc, 0, 0, 0);
            if (lr < NHEAD) {
                int j0 = jt * 16 + kg * 4;
#pragma unroll
                for (int r = 0; r < 4; r++)
                    if (s_mask[j0 + r])
                        s_scores[lr][j0 + r] += 0.125f * acc[r];
            }
        }
    }
    __syncthreads();

    // ---- softmax per head (wave w -> heads w, w+4, w+8); S=160 = 64+64+32 ----
    for (int h = w; h < NHEAD; h += 4) {
        float v0 = s_scores[h][l];
        float v1 = s_scores[h][l + 64];
        float v2 = (l < 32) ? s_scores[h][l + 128] : -INFINITY;
        float mx = fmaxf(v0, fmaxf(v1, v2));
#pragma unroll
        for (int mm = 32; mm >= 1; mm >>= 1) mx = fmaxf(mx, __shfl_xor(mx, mm, 64));
        float e0 = expf(v0 - mx), e1 = expf(v1 - mx);
        float e2 = (l < 32) ? expf(v2 - mx) : 0.f;
        float sm = e0 + e1 + e2;
#pragma unroll
        for (int mm = 32; mm >= 1; mm >>= 1) sm += __shfl_xor(sm, mm, 64);
        float inv = 1.0f / sm;
        s_scores[h][l]      = e0 * inv;
        s_scores[h][l + 64] = e1 * inv;
        if (l < 32) s_scores[h][l + 128] = e2 * inv;
    }
    __syncthreads();

    // ---- pass 2: wave w owns heads 3w..3w+2; lane = channel; float2 probs ----
    {
        int h0 = w * 3;
        float av0 = 0.f, av1 = 0.f, av2 = 0.f;
        float pe0 = 0.f, pe1 = 0.f, pe2 = 0.f;
        const __hip_bfloat16* vbp = v_ws + (size_t)b * SS * HH + h0 * DHEAD + l;
        const float* er = e_row + l;
#pragma unroll 2
        for (int j0 = 0; j0 < SS; j0 += 2) {
            float2 p0 = *(const float2*)(&s_scores[h0][j0]);
            float2 p1 = *(const float2*)(&s_scores[h0 + 1][j0]);
            float2 p2 = *(const float2*)(&s_scores[h0 + 2][j0]);
            const __hip_bfloat16* vp = vbp + (size_t)j0 * HH;
            av0 += p0.x * __bfloat162float(vp[0])
                 + p0.y * __bfloat162float(vp[HH]);
            av1 += p1.x * __bfloat162float(vp[DHEAD])
                 + p1.y * __bfloat162float(vp[HH + DHEAD]);
            av2 += p2.x * __bfloat162float(vp[2 * DHEAD])
                 + p2.y * __bfloat162float(vp[HH + 2 * DHEAD]);
            float ev0 = er[(size_t)j0 * DEPTH];
            float ev1 = er[(size_t)(j0 + 1) * DEPTH];
            pe0 += p0.x * ev0 + p0.y * ev1;
            pe1 += p1.x * ev0 + p1.y * ev1;
            pe2 += p2.x * ev0 + p2.y * ev1;
        }
        s_pe[h0][l]     = pe0;
        s_pe[h0 + 1][l] = pe1;
        s_pe[h0 + 2][l] = pe2;
        s_ctx[h0 * DHEAD + l]       = av0;
        s_ctx[(h0 + 1) * DHEAD + l] = av1;
        s_ctx[(h0 + 2) * DHEAD + l] = av2;
    }
    __syncthreads();

    // ---- ctx_e = pe_h @ Wev_h + bev ; residual add ----
    for (int mdx = tid; mdx < HH; mdx += 256) {
        int h = mdx >> 6;
        const float* pep = &s_pe[h][0];
        float sum = 0.f;
#pragma unroll
        for (int d = 0; d < DEPTH; d++) sum += pep[d] * Wev[(size_t)d * HH + mdx];
        float ctx = s_ctx[mdx] + (sum + bev[mdx]);
        s_x[mdx] = token[(size_t)bi * HH + mdx] + ctx;
    }
    __syncthreads();

    // ---- LayerNorm over H ----
    float lsum = 0.f, lsq = 0.f;
    for (int c = tid; c < HH; c += 256) {
        float x = s_x[c];
        lsum += x; lsq += x * x;
    }
#pragma unroll
    for (int mm = 32; mm >= 1; mm >>= 1) {
        lsum += __shfl_xor(lsum, mm, 64);
        lsq  += __shfl_xor(lsq,  mm, 64);
    }
    if (l == 0) { s_red[w] = lsum; s_red[4 + w] = lsq; }
    __syncthreads();
    float tsum = s_red[0] + s_red[1] + s_red[2] + s_red[3];
    float tsq  = s_red[4] + s_red[5] + s_red[6] + s_red[7];
    float mu  = tsum / HH;
    float var = tsq / HH - mu * mu;
    float rstd = rsqrtf(var + EPS_C);
    for (int c = tid; c < HH; c += 256)
        out[(size_t)bi * HH + c] = (s_x[c] - mu) * rstd * ln_g[c] + ln_b[c];
}

extern "C" void kernel_launch(void* const* d_in, const int* in_sizes, int n_in,
                              void* d_out, int out_size, void* d_ws, size_t ws_size,
                              hipStream_t stream) {
    const float* token = (const float*)d_in[0];
    const float* edge  = (const float*)d_in[1];
    const int*   mask  = (const int*)d_in[2];
    const float* Wq = (const float*)d_in[3];  const float* bq = (const float*)d_in[4];
    const float* Wk = (const float*)d_in[5];  const float* bk = (const float*)d_in[6];
    const float* Wv = (const float*)d_in[7];  const float* bv = (const float*)d_in[8];
    const float* Wek = (const float*)d_in[9];  const float* bek = (const float*)d_in[10];
    const float* Wev = (const float*)d_in[11]; const float* bev = (const float*)d_in[12];
    const float* ln_g = (const float*)d_in[13]; const float* ln_b = (const float*)d_in[14];
    float* out = (float*)d_out;

    // ws layout (10.875 MiB, proven): [qb][kb][vb][Xb][WT]
    // sc f16 (4.69 MiB) aliases [Xb..WT] (5.25 MiB) after gemm_qkv.
    // qek bf16 (1.875 MiB) aliases kb after scores_gemm (kb dead then).
    __hip_bfloat16* qb = (__hip_bfloat16*)d_ws;
    __hip_bfloat16* kb = qb + (size_t)BS * HH;
    __hip_bfloat16* vb = kb + (size_t)BS * HH;
    __hip_bfloat16* Xb = vb + (size_t)BS * HH;
    __hip_bfloat16* WT = Xb + (size_t)BS * HH;
    _Float16*       sc = (_Float16*)Xb;
    __hip_bfloat16* qek = kb;

    cast_x<<<(BS * HH / 4) / 256, 256, 0, stream>>>(token, Xb);
    transpose_cast_w<<<dim3(24, 24, 3), 256, 0, stream>>>(Wq, Wk, Wv, WT);
    gemm_qkv<<<dim3(BS / 128, HH / 64, 3), 256, 0, stream>>>(
        Xb, WT, bq, bk, bv, qb, kb, vb);
    scores_gemm<<<dim3(NHEAD, BB), 256, 0, stream>>>(qb, kb, sc);
    qek_slim<<<dim3(NHEAD, 10), 256, 0, stream>>>(qb, Wek, qek);
    attn_kernel<<<BS, 256, 0, stream>>>(token, edge, mask, qb, sc, vb, qek,
                                        bek, Wev, bev, ln_g, ln_b, out);
}